// Round 3
// baseline (1456.117 us; speedup 1.0000x reference)
//
#include <hip/hip_runtime.h>

// PureWaveAttention: B=2,T=2048,D=1024,H=16,NW=64,HD=64 — ALL FP32 I/O.
// Pipeline:
//  1) proj_wave (x2): qn/kn = normalize(sin((x@Wf+bf)*t + (x@Wp+bp))) fp32 [B,T,H,64]
//  2) gemm: v = x@Wv+bv  fp32 [B,T,D]  (layout == [B,T,H,HD])
//  3) attn: att[t] = scale[h]/sqrt(t+1) * sum_{s<=t} (qn[t].kn[s]) * v[s]  fp32 [B,T,D]
//  4) gemm: d_out = att@Wo+bo  fp32
// NUMERICS: threshold is 1.5e-2 ABSOLUTE with |ref| up to ~450 -> the whole
// path must be fp32 (no bf16/MFMA: 0.4% rel error would be ~1.8 abs).
// Phase f*t+p amplifies f-error by t<=2047 through sin -> keep f fp32-exact.

#define Bb 2
#define Tt 2048
#define Dd 1024
#define Hh 16

// ---------------------------------------------------------------------------
// Kernel 1: fused projection (f and p heads) + sin + L2-normalize epilogue.
// Tile: 64 t-rows x 64 cols (== one head). block 256 = 16x16, 4x4 per thread.
// ---------------------------------------------------------------------------
__global__ __launch_bounds__(256) void proj_wave_kernel(
    const float* __restrict__ X,
    const float* __restrict__ WF, const float* __restrict__ BF,
    const float* __restrict__ WP, const float* __restrict__ BP,
    float* __restrict__ OUT)
{
  __shared__ float As[64][20];
  __shared__ float Fs[16][68];
  __shared__ float Ps[16][68];
  const int tid = threadIdx.x;
  const int ty = tid >> 4, tx = tid & 15;
  const int tb = blockIdx.x, h = blockIdx.y, b = blockIdx.z;
  const int row0 = b * Tt + tb * 64;   // row in x [B*T, D]
  const int col0 = h * 64;             // col in W [D, H*NW]

  float accF[4][4] = {{0.f}};
  float accP[4][4] = {{0.f}};

  const int am = tid >> 2;             // 0..63 (A row)
  const int ak = (tid & 3) * 4;        // 0,4,8,12 (A k)
  const int wk = tid >> 4;             // 0..15 (W k-row)
  const int wn = (tid & 15) * 4;       // 0..60 (W col)

  for (int k0 = 0; k0 < Dd; k0 += 16) {
    float4 a = *(const float4*)&X[(size_t)(row0 + am) * Dd + k0 + ak];
    float4 f = *(const float4*)&WF[(size_t)(k0 + wk) * Dd + col0 + wn];
    float4 p = *(const float4*)&WP[(size_t)(k0 + wk) * Dd + col0 + wn];
    *(float4*)&As[am][ak] = a;
    *(float4*)&Fs[wk][wn] = f;
    *(float4*)&Ps[wk][wn] = p;
    __syncthreads();
    #pragma unroll
    for (int kk = 0; kk < 16; kk += 4) {
      float4 av[4], fv[4], pv[4];
      #pragma unroll
      for (int i = 0; i < 4; ++i) av[i] = *(const float4*)&As[ty * 4 + i][kk];
      #pragma unroll
      for (int d = 0; d < 4; ++d) {
        fv[d] = *(const float4*)&Fs[kk + d][tx * 4];
        pv[d] = *(const float4*)&Ps[kk + d][tx * 4];
      }
      const float* a_ = (const float*)av;
      const float* f_ = (const float*)fv;
      const float* p_ = (const float*)pv;
      #pragma unroll
      for (int i = 0; i < 4; ++i)
        #pragma unroll
        for (int d = 0; d < 4; ++d) {
          float aa = a_[i * 4 + d];
          #pragma unroll
          for (int j = 0; j < 4; ++j) {
            accF[i][j] = fmaf(aa, f_[d * 4 + j], accF[i][j]);
            accP[i][j] = fmaf(aa, p_[d * 4 + j], accP[i][j]);
          }
        }
    }
    __syncthreads();
  }

  float bF[4], bP[4];
  #pragma unroll
  for (int j = 0; j < 4; ++j) {
    bF[j] = BF[col0 + tx * 4 + j];
    bP[j] = BP[col0 + tx * 4 + j];
  }
  #pragma unroll
  for (int i = 0; i < 4; ++i) {
    const int t = tb * 64 + ty * 4 + i;
    const float tf = (float)t;
    float w[4];
    float ss = 0.f;
    #pragma unroll
    for (int j = 0; j < 4; ++j) {
      float ff = accF[i][j] + bF[j];
      float pp = accP[i][j] + bP[j];
      w[j] = sinf(fmaf(ff, tf, pp));
      ss += w[j] * w[j];
    }
    // reduce across the 16 lanes sharing this ty (lanes within one wave group)
    ss += __shfl_xor(ss, 1);
    ss += __shfl_xor(ss, 2);
    ss += __shfl_xor(ss, 4);
    ss += __shfl_xor(ss, 8);
    const float inv = 1.f / fmaxf(sqrtf(ss), 1e-12f);
    float4 o = make_float4(w[0] * inv, w[1] * inv, w[2] * inv, w[3] * inv);
    *(float4*)&OUT[((size_t)(b * Tt + t) * Hh + h) * 64 + tx * 4] = o;
  }
}

// ---------------------------------------------------------------------------
// Kernel 2/4: tiled GEMM  C[M,1024] = A[M,1024] @ W[1024,1024] + bias  (fp32)
// ---------------------------------------------------------------------------
__global__ __launch_bounds__(256) void gemm_kernel(
    const float* __restrict__ A, const float* __restrict__ W,
    const float* __restrict__ BIAS, float* __restrict__ OUT)
{
  __shared__ float As[64][20];
  __shared__ float Ws[16][68];
  const int tid = threadIdx.x;
  const int ty = tid >> 4, tx = tid & 15;
  const int m0 = blockIdx.x * 64, n0 = blockIdx.y * 64;

  float acc[4][4] = {{0.f}};

  const int am = tid >> 2;
  const int ak = (tid & 3) * 4;
  const int wk = tid >> 4;
  const int wn = (tid & 15) * 4;

  for (int k0 = 0; k0 < Dd; k0 += 16) {
    *(float4*)&As[am][ak] = *(const float4*)&A[(size_t)(m0 + am) * Dd + k0 + ak];
    *(float4*)&Ws[wk][wn] = *(const float4*)&W[(size_t)(k0 + wk) * Dd + n0 + wn];
    __syncthreads();
    #pragma unroll
    for (int kk = 0; kk < 16; kk += 4) {
      float4 av[4], wv[4];
      #pragma unroll
      for (int i = 0; i < 4; ++i) av[i] = *(const float4*)&As[ty * 4 + i][kk];
      #pragma unroll
      for (int d = 0; d < 4; ++d) wv[d] = *(const float4*)&Ws[kk + d][tx * 4];
      const float* a_ = (const float*)av;
      const float* w_ = (const float*)wv;
      #pragma unroll
      for (int i = 0; i < 4; ++i)
        #pragma unroll
        for (int d = 0; d < 4; ++d) {
          float aa = a_[i * 4 + d];
          #pragma unroll
          for (int j = 0; j < 4; ++j)
            acc[i][j] = fmaf(aa, w_[d * 4 + j], acc[i][j]);
        }
    }
    __syncthreads();
  }

  float bn[4];
  #pragma unroll
  for (int j = 0; j < 4; ++j) bn[j] = BIAS[n0 + tx * 4 + j];

  #pragma unroll
  for (int i = 0; i < 4; ++i) {
    const int m = m0 + ty * 4 + i;
    *(float4*)&OUT[(size_t)m * Dd + n0 + tx * 4] =
        make_float4(acc[i][0] + bn[0], acc[i][1] + bn[1],
                    acc[i][2] + bn[2], acc[i][3] + bn[3]);
  }
}

// ---------------------------------------------------------------------------
// Kernel 3: causal linear attention.
// block = (t-block of 64, h, b); 256 threads: 4 threads per t-row.
// att[t] = scale[h]/sqrt(t+1) * sum_{s<=t} (qn[t].kn[s]) * v[s]
// ---------------------------------------------------------------------------
__global__ __launch_bounds__(256) void attn_kernel(
    const float* __restrict__ QN, const float* __restrict__ KN,
    const float* __restrict__ V, const float* __restrict__ SCALE,
    float* __restrict__ ATT)
{
  __shared__ float Ks[64][64];
  __shared__ float Vs[64][64];
  const int tid = threadIdx.x;
  const int r = tid >> 2, part = tid & 3;
  const int tb = blockIdx.x, h = blockIdx.y, b = blockIdx.z;
  const int t = tb * 64 + r;

  float4 q4[4];
  {
    const float* qrow = &QN[((size_t)(b * Tt + t) * Hh + h) * 64 + part * 16];
    #pragma unroll
    for (int i = 0; i < 4; ++i) q4[i] = *(const float4*)&qrow[i * 4];
  }
  float4 acc[4];
  #pragma unroll
  for (int i = 0; i < 4; ++i) acc[i] = make_float4(0.f, 0.f, 0.f, 0.f);

  const int lsl = tid >> 4, lw = (tid & 15) * 4;

  for (int sb = 0; sb <= tb; ++sb) {
    #pragma unroll
    for (int l = 0; l < 4; ++l) {
      const int sl = lsl + l * 16;
      const int s = sb * 64 + sl;
      *(float4*)&Ks[sl][lw] = *(const float4*)&KN[((size_t)(b * Tt + s) * Hh + h) * 64 + lw];
      *(float4*)&Vs[sl][lw] = *(const float4*)&V[((size_t)(b * Tt + s)) * Dd + h * 64 + lw];
    }
    __syncthreads();
    const int slmax = (sb == tb) ? r : 63;
    for (int sl = 0; sl <= slmax; ++sl) {
      const float4* kr = (const float4*)&Ks[sl][part * 16];
      float dot = 0.f;
      #pragma unroll
      for (int i = 0; i < 4; ++i) {
        float4 kv = kr[i], qv = q4[i];
        dot = fmaf(qv.x, kv.x, dot);
        dot = fmaf(qv.y, kv.y, dot);
        dot = fmaf(qv.z, kv.z, dot);
        dot = fmaf(qv.w, kv.w, dot);
      }
      dot += __shfl_xor(dot, 1);
      dot += __shfl_xor(dot, 2);
      const float4* vr = (const float4*)&Vs[sl][part * 16];
      #pragma unroll
      for (int i = 0; i < 4; ++i) {
        float4 vv = vr[i];
        acc[i].x = fmaf(dot, vv.x, acc[i].x);
        acc[i].y = fmaf(dot, vv.y, acc[i].y);
        acc[i].z = fmaf(dot, vv.z, acc[i].z);
        acc[i].w = fmaf(dot, vv.w, acc[i].w);
      }
    }
    __syncthreads();
  }

  const float fac = SCALE[h] / sqrtf((float)(t + 1));
  float* orow = &ATT[((size_t)(b * Tt + t)) * Dd + h * 64 + part * 16];
  #pragma unroll
  for (int i = 0; i < 4; ++i) {
    float4 o = make_float4(acc[i].x * fac, acc[i].y * fac, acc[i].z * fac, acc[i].w * fac);
    *(float4*)&orow[i * 4] = o;
  }
}

// ---------------------------------------------------------------------------
extern "C" void kernel_launch(void* const* d_in, const int* in_sizes, int n_in,
                              void* d_out, int out_size, void* d_ws, size_t ws_size,
                              hipStream_t stream) {
  const float* x   = (const float*)d_in[0];
  const float* Wqf = (const float*)d_in[1];
  const float* bqf = (const float*)d_in[2];
  const float* Wkf = (const float*)d_in[3];
  const float* bkf = (const float*)d_in[4];
  const float* Wqp = (const float*)d_in[5];
  const float* bqp = (const float*)d_in[6];
  const float* Wkp = (const float*)d_in[7];
  const float* bkp = (const float*)d_in[8];
  const float* Wv  = (const float*)d_in[9];
  const float* bv  = (const float*)d_in[10];
  const float* Wo  = (const float*)d_in[11];
  const float* bo  = (const float*)d_in[12];
  const float* scale = (const float*)d_in[13];

  const size_t NTOK = (size_t)Bb * Tt * Dd;  // 4,194,304
  float* qn   = (float*)d_ws;          // 16 MB
  float* kn   = qn + NTOK;             // 16 MB
  float* vbuf = kn + NTOK;             // 16 MB
  float* att  = vbuf + NTOK;           // 16 MB  (total 64 MB of ws)

  dim3 gw(Tt / 64, Hh, Bb);  // (32,16,2)
  proj_wave_kernel<<<gw, 256, 0, stream>>>(x, Wqf, bqf, Wqp, bqp, qn);
  proj_wave_kernel<<<gw, 256, 0, stream>>>(x, Wkf, bkf, Wkp, bkp, kn);

  dim3 gg((Bb * Tt) / 64, Dd / 64);  // (64,16)
  gemm_kernel<<<gg, 256, 0, stream>>>(x, Wv, bv, vbuf);

  attn_kernel<<<gw, 256, 0, stream>>>(qn, kn, vbuf, scale, att);

  gemm_kernel<<<gg, 256, 0, stream>>>(att, Wo, bo, (float*)d_out);
}

// Round 4
// 854.192 us; speedup vs baseline: 1.7047x; 1.7047x over previous
//
#include <hip/hip_runtime.h>

// PureWaveAttention: B=2,T=2048,D=1024,H=16,NW=64,HD=64 — ALL FP32 I/O.
// Pipeline:
//  1) proj_wave (x2): qn/kn = normalize(sin((x@Wf+bf)*t + (x@Wp+bp))) fp32 [B,T,H,64]
//  2) gemm: v = x@Wv+bv  fp32 [B,T,D]
//  3) CHUNKED LINEAR ATTENTION (score is a plain dot product =>
//     sum_{s<=t}(q_t.k_s)v_s = q_t . M_t, M_t = sum_{s<=t} k_s v_s^T):
//     a) chunk_kv:  G_c = K_c^T V_c          (per 64-chunk, 64x64)
//     b) prefix:    M_c = sum_{c'<c} G_c'    (in-place exclusive prefix)
//     c) attn_chunk: O_c = (Q_c M_c + tril(Q_c K_c^T) V_c) * scale/sqrt(t+1)
//  4) gemm: d_out = att@Wo+bo  fp32
// ws layout (64 MB): qn | kn | vbuf | G(prefixed in place). att ALIASES qn:
// block (c,h) is the only reader of qn slab (t in c, head h) and loads it to
// LDS before writing att to the same addresses -> race-free.

#define Bb 2
#define Tt 2048
#define Dd 1024
#define Hh 16
#define NC 32   // T/64 chunks

// ---------------------------------------------------------------------------
// Kernel 1: fused projection (f and p heads) + sin + L2-normalize epilogue.
// ---------------------------------------------------------------------------
__global__ __launch_bounds__(256) void proj_wave_kernel(
    const float* __restrict__ X,
    const float* __restrict__ WF, const float* __restrict__ BF,
    const float* __restrict__ WP, const float* __restrict__ BP,
    float* __restrict__ OUT)
{
  __shared__ float As[64][20];
  __shared__ float Fs[16][68];
  __shared__ float Ps[16][68];
  const int tid = threadIdx.x;
  const int ty = tid >> 4, tx = tid & 15;
  const int tb = blockIdx.x, h = blockIdx.y, b = blockIdx.z;
  const int row0 = b * Tt + tb * 64;
  const int col0 = h * 64;

  float accF[4][4] = {{0.f}};
  float accP[4][4] = {{0.f}};

  const int am = tid >> 2;
  const int ak = (tid & 3) * 4;
  const int wk = tid >> 4;
  const int wn = (tid & 15) * 4;

  for (int k0 = 0; k0 < Dd; k0 += 16) {
    float4 a = *(const float4*)&X[(size_t)(row0 + am) * Dd + k0 + ak];
    float4 f = *(const float4*)&WF[(size_t)(k0 + wk) * Dd + col0 + wn];
    float4 p = *(const float4*)&WP[(size_t)(k0 + wk) * Dd + col0 + wn];
    *(float4*)&As[am][ak] = a;
    *(float4*)&Fs[wk][wn] = f;
    *(float4*)&Ps[wk][wn] = p;
    __syncthreads();
    #pragma unroll
    for (int kk = 0; kk < 16; kk += 4) {
      float4 av[4], fv[4], pv[4];
      #pragma unroll
      for (int i = 0; i < 4; ++i) av[i] = *(const float4*)&As[ty * 4 + i][kk];
      #pragma unroll
      for (int d = 0; d < 4; ++d) {
        fv[d] = *(const float4*)&Fs[kk + d][tx * 4];
        pv[d] = *(const float4*)&Ps[kk + d][tx * 4];
      }
      const float* a_ = (const float*)av;
      const float* f_ = (const float*)fv;
      const float* p_ = (const float*)pv;
      #pragma unroll
      for (int i = 0; i < 4; ++i)
        #pragma unroll
        for (int d = 0; d < 4; ++d) {
          float aa = a_[i * 4 + d];
          #pragma unroll
          for (int j = 0; j < 4; ++j) {
            accF[i][j] = fmaf(aa, f_[d * 4 + j], accF[i][j]);
            accP[i][j] = fmaf(aa, p_[d * 4 + j], accP[i][j]);
          }
        }
    }
    __syncthreads();
  }

  float bF[4], bP[4];
  #pragma unroll
  for (int j = 0; j < 4; ++j) {
    bF[j] = BF[col0 + tx * 4 + j];
    bP[j] = BP[col0 + tx * 4 + j];
  }
  #pragma unroll
  for (int i = 0; i < 4; ++i) {
    const int t = tb * 64 + ty * 4 + i;
    const float tf = (float)t;
    float w[4];
    float ss = 0.f;
    #pragma unroll
    for (int j = 0; j < 4; ++j) {
      float ff = accF[i][j] + bF[j];
      float pp = accP[i][j] + bP[j];
      w[j] = sinf(fmaf(ff, tf, pp));
      ss += w[j] * w[j];
    }
    ss += __shfl_xor(ss, 1);
    ss += __shfl_xor(ss, 2);
    ss += __shfl_xor(ss, 4);
    ss += __shfl_xor(ss, 8);
    const float inv = 1.f / fmaxf(sqrtf(ss), 1e-12f);
    float4 o = make_float4(w[0] * inv, w[1] * inv, w[2] * inv, w[3] * inv);
    *(float4*)&OUT[((size_t)(b * Tt + t) * Hh + h) * 64 + tx * 4] = o;
  }
}

// ---------------------------------------------------------------------------
// Kernel 2/7: tiled GEMM  C[M,1024] = A[M,1024] @ W[1024,1024] + bias  (fp32)
// ---------------------------------------------------------------------------
__global__ __launch_bounds__(256) void gemm_kernel(
    const float* __restrict__ A, const float* __restrict__ W,
    const float* __restrict__ BIAS, float* __restrict__ OUT)
{
  __shared__ float As[64][20];
  __shared__ float Ws[16][68];
  const int tid = threadIdx.x;
  const int ty = tid >> 4, tx = tid & 15;
  const int m0 = blockIdx.x * 64, n0 = blockIdx.y * 64;

  float acc[4][4] = {{0.f}};

  const int am = tid >> 2;
  const int ak = (tid & 3) * 4;
  const int wk = tid >> 4;
  const int wn = (tid & 15) * 4;

  for (int k0 = 0; k0 < Dd; k0 += 16) {
    *(float4*)&As[am][ak] = *(const float4*)&A[(size_t)(m0 + am) * Dd + k0 + ak];
    *(float4*)&Ws[wk][wn] = *(const float4*)&W[(size_t)(k0 + wk) * Dd + n0 + wn];
    __syncthreads();
    #pragma unroll
    for (int kk = 0; kk < 16; kk += 4) {
      float4 av[4], wv[4];
      #pragma unroll
      for (int i = 0; i < 4; ++i) av[i] = *(const float4*)&As[ty * 4 + i][kk];
      #pragma unroll
      for (int d = 0; d < 4; ++d) wv[d] = *(const float4*)&Ws[kk + d][tx * 4];
      const float* a_ = (const float*)av;
      const float* w_ = (const float*)wv;
      #pragma unroll
      for (int i = 0; i < 4; ++i)
        #pragma unroll
        for (int d = 0; d < 4; ++d) {
          float aa = a_[i * 4 + d];
          #pragma unroll
          for (int j = 0; j < 4; ++j)
            acc[i][j] = fmaf(aa, w_[d * 4 + j], acc[i][j]);
        }
    }
    __syncthreads();
  }

  float bn[4];
  #pragma unroll
  for (int j = 0; j < 4; ++j) bn[j] = BIAS[n0 + tx * 4 + j];

  #pragma unroll
  for (int i = 0; i < 4; ++i) {
    const int m = m0 + ty * 4 + i;
    *(float4*)&OUT[(size_t)m * Dd + n0 + tx * 4] =
        make_float4(acc[i][0] + bn[0], acc[i][1] + bn[1],
                    acc[i][2] + bn[2], acc[i][3] + bn[3]);
  }
}

// ---------------------------------------------------------------------------
// Kernel 3a: G_c[w][d] = sum_{s in chunk c} K[s][w] * V[s][d]   (64x64)
// Contraction over s (row index) -> both operands read as rows, no transpose.
// ---------------------------------------------------------------------------
__global__ __launch_bounds__(256) void chunk_kv_kernel(
    const float* __restrict__ KN, const float* __restrict__ V,
    float* __restrict__ G)
{
  __shared__ float Ks[64][64];
  __shared__ float Vs[64][64];
  const int tid = threadIdx.x;
  const int c = blockIdx.x, h = blockIdx.y, b = blockIdx.z;
  const int s0 = c * 64;

  const int lr = tid >> 2;          // 0..63 (s row)
  const int lc = (tid & 3) * 16;    // col base
  {
    const float* krow = &KN[((size_t)(b * Tt + s0 + lr) * Hh + h) * 64 + lc];
    const float* vrow = &V[((size_t)(b * Tt + s0 + lr)) * Dd + h * 64 + lc];
    #pragma unroll
    for (int i = 0; i < 4; ++i) {
      *(float4*)&Ks[lr][lc + i * 4] = *(const float4*)&krow[i * 4];
      *(float4*)&Vs[lr][lc + i * 4] = *(const float4*)&vrow[i * 4];
    }
  }
  __syncthreads();

  const int ty = tid >> 4, tx = tid & 15;   // w-tile, d-tile
  float g[4][4] = {{0.f}};
  #pragma unroll 4
  for (int s = 0; s < 64; ++s) {
    float4 kv = *(const float4*)&Ks[s][ty * 4];
    float4 vv = *(const float4*)&Vs[s][tx * 4];
    const float* k_ = (const float*)&kv;
    const float* v_ = (const float*)&vv;
    #pragma unroll
    for (int i = 0; i < 4; ++i)
      #pragma unroll
      for (int j = 0; j < 4; ++j)
        g[i][j] = fmaf(k_[i], v_[j], g[i][j]);
  }

  float* Gp = G + (((size_t)(b * Hh + h) * NC + c) << 12);  // *4096
  #pragma unroll
  for (int i = 0; i < 4; ++i)
    *(float4*)&Gp[(ty * 4 + i) * 64 + tx * 4] =
        make_float4(g[i][0], g[i][1], g[i][2], g[i][3]);
}

// ---------------------------------------------------------------------------
// Kernel 3b: in-place exclusive prefix over the NC chunk matrices per (b,h).
// Each thread owns 16 disjoint floats of the 64x64 matrix.
// ---------------------------------------------------------------------------
__global__ __launch_bounds__(256) void prefix_kernel(float* __restrict__ G)
{
  const int h = blockIdx.x, b = blockIdx.y;
  float* base = G + (((size_t)(b * Hh + h) * NC) << 12);
  const int off = threadIdx.x * 16;
  float4 a0 = make_float4(0.f, 0.f, 0.f, 0.f);
  float4 a1 = a0, a2 = a0, a3 = a0;
  for (int c = 0; c < NC; ++c) {
    float* p = base + ((size_t)c << 12) + off;
    float4 g0 = *(float4*)&p[0];
    float4 g1 = *(float4*)&p[4];
    float4 g2 = *(float4*)&p[8];
    float4 g3 = *(float4*)&p[12];
    *(float4*)&p[0]  = a0;
    *(float4*)&p[4]  = a1;
    *(float4*)&p[8]  = a2;
    *(float4*)&p[12] = a3;
    a0.x += g0.x; a0.y += g0.y; a0.z += g0.z; a0.w += g0.w;
    a1.x += g1.x; a1.y += g1.y; a1.z += g1.z; a1.w += g1.w;
    a2.x += g2.x; a2.y += g2.y; a2.z += g2.z; a2.w += g2.w;
    a3.x += g3.x; a3.y += g3.y; a3.z += g3.z; a3.w += g3.w;
  }
}

// ---------------------------------------------------------------------------
// Kernel 3c: O_c = (Q_c M_c + tril(Q_c K_c^T) V_c) * scale[h]/sqrt(t+1)
// C1+C2 fused (shared Q fragment, contraction over w); S transposed via LDS
// (reusing the M buffer); C3 contracts over s.
// ---------------------------------------------------------------------------
__global__ __launch_bounds__(256) void attn_chunk_kernel(
    const float* __restrict__ QN, const float* __restrict__ KN,
    const float* __restrict__ V, const float* __restrict__ M,
    const float* __restrict__ SCALE, float* __restrict__ ATT)
{
  __shared__ float Qt[64][68];   // Qt[w][t]  (transposed)
  __shared__ float Kt[64][68];   // Kt[w][s]  (transposed)
  __shared__ float SM[64][68];   // M[w][d], then S_t[s][t]
  __shared__ float Vs[64][64];   // Vs[s][d]
  const int tid = threadIdx.x;
  const int c = blockIdx.x, h = blockIdx.y, b = blockIdx.z;
  const int t0 = c * 64;

  // --- stage 0: loads ---
  const int lr = tid >> 2;          // 0..63
  const int lc = (tid & 3) * 16;
  {
    const float* qrow = &QN[((size_t)(b * Tt + t0 + lr) * Hh + h) * 64 + lc];
    const float* krow = &KN[((size_t)(b * Tt + t0 + lr) * Hh + h) * 64 + lc];
    const float* vrow = &V[((size_t)(b * Tt + t0 + lr)) * Dd + h * 64 + lc];
    const float* mrow = &M[(((size_t)(b * Hh + h) * NC + c) << 12) + lr * 64 + lc];
    #pragma unroll
    for (int i = 0; i < 4; ++i) {
      float4 q = *(const float4*)&qrow[i * 4];
      float4 k = *(const float4*)&krow[i * 4];
      Qt[lc + i * 4 + 0][lr] = q.x; Qt[lc + i * 4 + 1][lr] = q.y;
      Qt[lc + i * 4 + 2][lr] = q.z; Qt[lc + i * 4 + 3][lr] = q.w;
      Kt[lc + i * 4 + 0][lr] = k.x; Kt[lc + i * 4 + 1][lr] = k.y;
      Kt[lc + i * 4 + 2][lr] = k.z; Kt[lc + i * 4 + 3][lr] = k.w;
      *(float4*)&Vs[lr][lc + i * 4] = *(const float4*)&vrow[i * 4];
      *(float4*)&SM[lr][lc + i * 4] = *(const float4*)&mrow[i * 4];
    }
  }
  __syncthreads();

  const int ty = tid >> 4, tx = tid & 15;  // t-tile / (d|s)-tile
  float o[4][4]  = {{0.f}};   // O[t][d]
  float sc[4][4] = {{0.f}};   // S[t][s]

  // --- C1+C2: O = Q*M, S = Q*K^T (both contract over w, shared Q frag) ---
  #pragma unroll 4
  for (int w = 0; w < 64; ++w) {
    float4 qv = *(const float4*)&Qt[w][ty * 4];
    float4 mv = *(const float4*)&SM[w][tx * 4];
    float4 kv = *(const float4*)&Kt[w][tx * 4];
    const float* q_ = (const float*)&qv;
    const float* m_ = (const float*)&mv;
    const float* k_ = (const float*)&kv;
    #pragma unroll
    for (int i = 0; i < 4; ++i) {
      float qq = q_[i];
      #pragma unroll
      for (int j = 0; j < 4; ++j) {
        o[i][j]  = fmaf(qq, m_[j], o[i][j]);
        sc[i][j] = fmaf(qq, k_[j], sc[i][j]);
      }
    }
  }
  __syncthreads();   // all M reads done before SM is overwritten with S_t

  // --- write masked S transposed: SM[s][t] ---
  #pragma unroll
  for (int i = 0; i < 4; ++i) {
    const int lt = ty * 4 + i;
    #pragma unroll
    for (int j = 0; j < 4; ++j) {
      const int ls = tx * 4 + j;
      SM[ls][lt] = (ls <= lt) ? sc[i][j] : 0.f;
    }
  }
  __syncthreads();

  // --- C3: O += S*V (contract over s) ---
  #pragma unroll 4
  for (int s = 0; s < 64; ++s) {
    float4 sv = *(const float4*)&SM[s][ty * 4];
    float4 vv = *(const float4*)&Vs[s][tx * 4];
    const float* s_ = (const float*)&sv;
    const float* v_ = (const float*)&vv;
    #pragma unroll
    for (int i = 0; i < 4; ++i)
      #pragma unroll
      for (int j = 0; j < 4; ++j)
        o[i][j] = fmaf(s_[i], v_[j], o[i][j]);
  }

  // --- epilogue: scale and store ---
  const float sch = SCALE[h];
  #pragma unroll
  for (int i = 0; i < 4; ++i) {
    const int t = t0 + ty * 4 + i;
    const float fac = sch / sqrtf((float)(t + 1));
    *(float4*)&ATT[((size_t)(b * Tt + t)) * Dd + h * 64 + tx * 4] =
        make_float4(o[i][0] * fac, o[i][1] * fac, o[i][2] * fac, o[i][3] * fac);
  }
}

// ---------------------------------------------------------------------------
extern "C" void kernel_launch(void* const* d_in, const int* in_sizes, int n_in,
                              void* d_out, int out_size, void* d_ws, size_t ws_size,
                              hipStream_t stream) {
  const float* x   = (const float*)d_in[0];
  const float* Wqf = (const float*)d_in[1];
  const float* bqf = (const float*)d_in[2];
  const float* Wkf = (const float*)d_in[3];
  const float* bkf = (const float*)d_in[4];
  const float* Wqp = (const float*)d_in[5];
  const float* bqp = (const float*)d_in[6];
  const float* Wkp = (const float*)d_in[7];
  const float* bkp = (const float*)d_in[8];
  const float* Wv  = (const float*)d_in[9];
  const float* bv  = (const float*)d_in[10];
  const float* Wo  = (const float*)d_in[11];
  const float* bo  = (const float*)d_in[12];
  const float* scale = (const float*)d_in[13];

  const size_t NTOK = (size_t)Bb * Tt * Dd;  // 4,194,304
  float* qn   = (float*)d_ws;          // 16 MB
  float* kn   = qn + NTOK;             // 16 MB
  float* vbuf = kn + NTOK;             // 16 MB
  float* G    = vbuf + NTOK;           // 16 MB (32 bh * 32 c * 4096)
  float* att  = qn;                    // ALIAS (safe: see header comment)

  dim3 gw(Tt / 64, Hh, Bb);  // (32,16,2)
  proj_wave_kernel<<<gw, 256, 0, stream>>>(x, Wqf, bqf, Wqp, bqp, qn);
  proj_wave_kernel<<<gw, 256, 0, stream>>>(x, Wkf, bkf, Wkp, bkp, kn);

  dim3 gg((Bb * Tt) / 64, Dd / 64);  // (64,16)
  gemm_kernel<<<gg, 256, 0, stream>>>(x, Wv, bv, vbuf);

  chunk_kv_kernel<<<dim3(NC, Hh, Bb), 256, 0, stream>>>(kn, vbuf, G);
  prefix_kernel<<<dim3(Hh, Bb), 256, 0, stream>>>(G);
  attn_chunk_kernel<<<dim3(NC, Hh, Bb), 256, 0, stream>>>(qn, kn, vbuf, G, scale, att);

  gemm_kernel<<<gg, 256, 0, stream>>>(att, Wo, bo, (float*)d_out);
}

// Round 5
// 837.895 us; speedup vs baseline: 1.7378x; 1.0194x over previous
//
#include <hip/hip_runtime.h>

// PureWaveAttention: B=2,T=2048,D=1024,H=16,NW=64,HD=64 — ALL FP32 I/O.
// Pipeline:
//  1) proj_wave2: qn/kn = normalize(sin((x@Wf+bf)*t + (x@Wp+bp))) fp32 [B,T,H,64]
//     (q and k merged in one launch; 128x64 tiles, BK=32, 8x(4+4) reg block)
//  2) gemm: v = x@Wv+bv  fp32 [B,T,D]   (128x128 tile, BK=32, 8x8 reg block)
//  3) CHUNKED LINEAR ATTENTION:
//     a) chunk_kv:  G_c = K_c^T V_c
//     b) prefix:    M_c = sum_{c'<c} G_c'  (in-place exclusive prefix)
//     c) attn_chunk: O_c = (Q_c M_c + tril(Q_c K_c^T) V_c) * scale/sqrt(t+1)
//  4) gemm: d_out = att@Wo+bo
// ws (64 MB): qn | kn | vbuf | G. att ALIASES qn (block (c,h) is sole reader
// of its qn slab and loads it to LDS before overwriting with att).

#define Bb 2
#define Tt 2048
#define Dd 1024
#define Hh 16
#define NC 32   // T/64 chunks

// ---------------------------------------------------------------------------
// Kernel 1: fused q+k projection + sin + L2-normalize.
// Tile 128(t) x 64(head cols), BK=32. Thread: rows {ty*4+i, 64+ty*4+i},
// cols tx*4..+3 for both F and P. blockIdx.y = h | (which<<4).
// ---------------------------------------------------------------------------
__global__ __launch_bounds__(256, 3) void proj_wave2_kernel(
    const float* __restrict__ X,
    const float* __restrict__ Wqf, const float* __restrict__ bqf,
    const float* __restrict__ Wqp, const float* __restrict__ bqp,
    const float* __restrict__ Wkf, const float* __restrict__ bkf,
    const float* __restrict__ Wkp, const float* __restrict__ bkp,
    float* __restrict__ QN, float* __restrict__ KN)
{
  __shared__ float As[128][36];   // [m][k], pad 36 (144B, 16B-aligned)
  __shared__ float Fs[32][68];    // [k][n]
  __shared__ float Ps[32][68];

  const int tid = threadIdx.x;
  const int ty = tid >> 4, tx = tid & 15;
  const int mb = blockIdx.x;                 // t-tile (0..15)
  const int which = blockIdx.y >> 4;         // 0=q, 1=k
  const int h = blockIdx.y & 15;
  const int b = blockIdx.z;
  const float* WF = which ? Wkf : Wqf;
  const float* BF = which ? bkf : bqf;
  const float* WP = which ? Wkp : Wqp;
  const float* BP = which ? bkp : bqp;
  float* OUT = which ? KN : QN;

  const int row0 = b * Tt + mb * 128;
  const int col0 = h * 64;

  float oF[8][4] = {{0.f}};
  float oP[8][4] = {{0.f}};

  for (int k0 = 0; k0 < Dd; k0 += 32) {
    // stage A: 128x32 (1024 float4, 4/thread)
    #pragma unroll
    for (int j = 0; j < 4; ++j) {
      const int idx = tid + j * 256;
      const int r = idx >> 3, c4 = (idx & 7) * 4;
      *(float4*)&As[r][c4] = *(const float4*)&X[(size_t)(row0 + r) * Dd + k0 + c4];
    }
    // stage F,P: 32x64 each (512 float4, 2/thread)
    #pragma unroll
    for (int j = 0; j < 2; ++j) {
      const int idx = tid + j * 256;
      const int kr = idx >> 4, c4 = (idx & 15) * 4;
      *(float4*)&Fs[kr][c4] = *(const float4*)&WF[(size_t)(k0 + kr) * Dd + col0 + c4];
      *(float4*)&Ps[kr][c4] = *(const float4*)&WP[(size_t)(k0 + kr) * Dd + col0 + c4];
    }
    __syncthreads();

    for (int kk = 0; kk < 32; kk += 4) {
      float4 a4[8], ff[4], pp[4];
      #pragma unroll
      for (int i = 0; i < 4; ++i) {
        a4[i]     = *(const float4*)&As[ty * 4 + i][kk];
        a4[4 + i] = *(const float4*)&As[64 + ty * 4 + i][kk];
      }
      #pragma unroll
      for (int j = 0; j < 4; ++j) {
        ff[j] = *(const float4*)&Fs[kk + j][tx * 4];
        pp[j] = *(const float4*)&Ps[kk + j][tx * 4];
      }
      #pragma unroll
      for (int j = 0; j < 4; ++j) {
        const float* f_ = (const float*)&ff[j];
        const float* p_ = (const float*)&pp[j];
        #pragma unroll
        for (int i = 0; i < 8; ++i) {
          const float aa = ((const float*)&a4[i])[j];
          #pragma unroll
          for (int n = 0; n < 4; ++n) {
            oF[i][n] = fmaf(aa, f_[n], oF[i][n]);
            oP[i][n] = fmaf(aa, p_[n], oP[i][n]);
          }
        }
      }
    }
    __syncthreads();
  }

  float bF[4], bP[4];
  #pragma unroll
  for (int j = 0; j < 4; ++j) {
    bF[j] = BF[col0 + tx * 4 + j];
    bP[j] = BP[col0 + tx * 4 + j];
  }
  #pragma unroll
  for (int i = 0; i < 8; ++i) {
    const int r = (i < 4) ? (ty * 4 + i) : (64 + ty * 4 + i - 4);
    const int t = mb * 128 + r;
    const float tf = (float)t;
    float w[4];
    float ss = 0.f;
    #pragma unroll
    for (int j = 0; j < 4; ++j) {
      const float fv = oF[i][j] + bF[j];
      const float pv = oP[i][j] + bP[j];
      w[j] = sinf(fmaf(fv, tf, pv));
      ss += w[j] * w[j];
    }
    ss += __shfl_xor(ss, 1);
    ss += __shfl_xor(ss, 2);
    ss += __shfl_xor(ss, 4);
    ss += __shfl_xor(ss, 8);
    const float inv = 1.f / fmaxf(sqrtf(ss), 1e-12f);
    *(float4*)&OUT[((size_t)(b * Tt + t) * Hh + h) * 64 + tx * 4] =
        make_float4(w[0] * inv, w[1] * inv, w[2] * inv, w[3] * inv);
  }
}

// ---------------------------------------------------------------------------
// Kernel 2/7: tiled GEMM  C[M,1024] = A[M,1024] @ W[1024,1024] + bias (fp32)
// 128x128 tile, BK=32. Thread: rows {ty*4+i, 64+ty*4+i}, cols {tx*4, 64+tx*4}.
// ---------------------------------------------------------------------------
__global__ __launch_bounds__(256, 3) void gemm_kernel(
    const float* __restrict__ A, const float* __restrict__ W,
    const float* __restrict__ BIAS, float* __restrict__ OUT)
{
  __shared__ float As[128][36];
  __shared__ float Ws[32][132];

  const int tid = threadIdx.x;
  const int ty = tid >> 4, tx = tid & 15;
  const int m0 = blockIdx.x * 128, n0 = blockIdx.y * 128;

  float acc[8][8] = {{0.f}};

  for (int k0 = 0; k0 < Dd; k0 += 32) {
    #pragma unroll
    for (int j = 0; j < 4; ++j) {
      const int idx = tid + j * 256;
      const int r = idx >> 3, c4 = (idx & 7) * 4;
      *(float4*)&As[r][c4] = *(const float4*)&A[(size_t)(m0 + r) * Dd + k0 + c4];
    }
    #pragma unroll
    for (int j = 0; j < 4; ++j) {
      const int idx = tid + j * 256;
      const int kr = idx >> 5, c4 = (idx & 31) * 4;
      *(float4*)&Ws[kr][c4] = *(const float4*)&W[(size_t)(k0 + kr) * Dd + n0 + c4];
    }
    __syncthreads();

    for (int kk = 0; kk < 32; kk += 4) {
      float4 a4[8], b4[2][4];
      #pragma unroll
      for (int i = 0; i < 4; ++i) {
        a4[i]     = *(const float4*)&As[ty * 4 + i][kk];
        a4[4 + i] = *(const float4*)&As[64 + ty * 4 + i][kk];
      }
      #pragma unroll
      for (int j = 0; j < 4; ++j) {
        b4[0][j] = *(const float4*)&Ws[kk + j][tx * 4];
        b4[1][j] = *(const float4*)&Ws[kk + j][64 + tx * 4];
      }
      #pragma unroll
      for (int j = 0; j < 4; ++j) {
        const float* b0 = (const float*)&b4[0][j];
        const float* b1 = (const float*)&b4[1][j];
        #pragma unroll
        for (int i = 0; i < 8; ++i) {
          const float aa = ((const float*)&a4[i])[j];
          #pragma unroll
          for (int n = 0; n < 4; ++n) {
            acc[i][n]     = fmaf(aa, b0[n], acc[i][n]);
            acc[i][4 + n] = fmaf(aa, b1[n], acc[i][4 + n]);
          }
        }
      }
    }
    __syncthreads();
  }

  float bn[8];
  #pragma unroll
  for (int j = 0; j < 4; ++j) {
    bn[j]     = BIAS[n0 + tx * 4 + j];
    bn[4 + j] = BIAS[n0 + 64 + tx * 4 + j];
  }
  #pragma unroll
  for (int i = 0; i < 8; ++i) {
    const int r = (i < 4) ? (ty * 4 + i) : (64 + ty * 4 + i - 4);
    const size_t m = (size_t)(m0 + r);
    *(float4*)&OUT[m * Dd + n0 + tx * 4] =
        make_float4(acc[i][0] + bn[0], acc[i][1] + bn[1],
                    acc[i][2] + bn[2], acc[i][3] + bn[3]);
    *(float4*)&OUT[m * Dd + n0 + 64 + tx * 4] =
        make_float4(acc[i][4] + bn[4], acc[i][5] + bn[5],
                    acc[i][6] + bn[6], acc[i][7] + bn[7]);
  }
}

// ---------------------------------------------------------------------------
// Kernel 3a: G_c[w][d] = sum_{s in chunk c} K[s][w] * V[s][d]   (64x64)
// ---------------------------------------------------------------------------
__global__ __launch_bounds__(256) void chunk_kv_kernel(
    const float* __restrict__ KN, const float* __restrict__ V,
    float* __restrict__ G)
{
  __shared__ float Ks[64][64];
  __shared__ float Vs[64][64];
  const int tid = threadIdx.x;
  const int c = blockIdx.x, h = blockIdx.y, b = blockIdx.z;
  const int s0 = c * 64;

  const int lr = tid >> 2;
  const int lc = (tid & 3) * 16;
  {
    const float* krow = &KN[((size_t)(b * Tt + s0 + lr) * Hh + h) * 64 + lc];
    const float* vrow = &V[((size_t)(b * Tt + s0 + lr)) * Dd + h * 64 + lc];
    #pragma unroll
    for (int i = 0; i < 4; ++i) {
      *(float4*)&Ks[lr][lc + i * 4] = *(const float4*)&krow[i * 4];
      *(float4*)&Vs[lr][lc + i * 4] = *(const float4*)&vrow[i * 4];
    }
  }
  __syncthreads();

  const int ty = tid >> 4, tx = tid & 15;
  float g[4][4] = {{0.f}};
  #pragma unroll 4
  for (int s = 0; s < 64; ++s) {
    float4 kv = *(const float4*)&Ks[s][ty * 4];
    float4 vv = *(const float4*)&Vs[s][tx * 4];
    const float* k_ = (const float*)&kv;
    const float* v_ = (const float*)&vv;
    #pragma unroll
    for (int i = 0; i < 4; ++i)
      #pragma unroll
      for (int j = 0; j < 4; ++j)
        g[i][j] = fmaf(k_[i], v_[j], g[i][j]);
  }

  float* Gp = G + (((size_t)(b * Hh + h) * NC + c) << 12);
  #pragma unroll
  for (int i = 0; i < 4; ++i)
    *(float4*)&Gp[(ty * 4 + i) * 64 + tx * 4] =
        make_float4(g[i][0], g[i][1], g[i][2], g[i][3]);
}

// ---------------------------------------------------------------------------
// Kernel 3b: in-place exclusive prefix over the NC chunk matrices per (b,h).
// ---------------------------------------------------------------------------
__global__ __launch_bounds__(256) void prefix_kernel(float* __restrict__ G)
{
  const int h = blockIdx.x, b = blockIdx.y;
  float* base = G + (((size_t)(b * Hh + h) * NC) << 12);
  const int off = threadIdx.x * 16;
  float4 a0 = make_float4(0.f, 0.f, 0.f, 0.f);
  float4 a1 = a0, a2 = a0, a3 = a0;
  for (int c = 0; c < NC; ++c) {
    float* p = base + ((size_t)c << 12) + off;
    float4 g0 = *(float4*)&p[0];
    float4 g1 = *(float4*)&p[4];
    float4 g2 = *(float4*)&p[8];
    float4 g3 = *(float4*)&p[12];
    *(float4*)&p[0]  = a0;
    *(float4*)&p[4]  = a1;
    *(float4*)&p[8]  = a2;
    *(float4*)&p[12] = a3;
    a0.x += g0.x; a0.y += g0.y; a0.z += g0.z; a0.w += g0.w;
    a1.x += g1.x; a1.y += g1.y; a1.z += g1.z; a1.w += g1.w;
    a2.x += g2.x; a2.y += g2.y; a2.z += g2.z; a2.w += g2.w;
    a3.x += g3.x; a3.y += g3.y; a3.z += g3.z; a3.w += g3.w;
  }
}

// ---------------------------------------------------------------------------
// Kernel 3c: O_c = (Q_c M_c + tril(Q_c K_c^T) V_c) * scale[h]/sqrt(t+1)
// ---------------------------------------------------------------------------
__global__ __launch_bounds__(256) void attn_chunk_kernel(
    const float* __restrict__ QN, const float* __restrict__ KN,
    const float* __restrict__ V, const float* __restrict__ M,
    const float* __restrict__ SCALE, float* __restrict__ ATT)
{
  __shared__ float Qt[64][68];
  __shared__ float Kt[64][68];
  __shared__ float SM[64][68];
  __shared__ float Vs[64][64];
  const int tid = threadIdx.x;
  const int c = blockIdx.x, h = blockIdx.y, b = blockIdx.z;
  const int t0 = c * 64;

  const int lr = tid >> 2;
  const int lc = (tid & 3) * 16;
  {
    const float* qrow = &QN[((size_t)(b * Tt + t0 + lr) * Hh + h) * 64 + lc];
    const float* krow = &KN[((size_t)(b * Tt + t0 + lr) * Hh + h) * 64 + lc];
    const float* vrow = &V[((size_t)(b * Tt + t0 + lr)) * Dd + h * 64 + lc];
    const float* mrow = &M[(((size_t)(b * Hh + h) * NC + c) << 12) + lr * 64 + lc];
    #pragma unroll
    for (int i = 0; i < 4; ++i) {
      float4 q = *(const float4*)&qrow[i * 4];
      float4 k = *(const float4*)&krow[i * 4];
      Qt[lc + i * 4 + 0][lr] = q.x; Qt[lc + i * 4 + 1][lr] = q.y;
      Qt[lc + i * 4 + 2][lr] = q.z; Qt[lc + i * 4 + 3][lr] = q.w;
      Kt[lc + i * 4 + 0][lr] = k.x; Kt[lc + i * 4 + 1][lr] = k.y;
      Kt[lc + i * 4 + 2][lr] = k.z; Kt[lc + i * 4 + 3][lr] = k.w;
      *(float4*)&Vs[lr][lc + i * 4] = *(const float4*)&vrow[i * 4];
      *(float4*)&SM[lr][lc + i * 4] = *(const float4*)&mrow[i * 4];
    }
  }
  __syncthreads();

  const int ty = tid >> 4, tx = tid & 15;
  float o[4][4]  = {{0.f}};
  float sc[4][4] = {{0.f}};

  #pragma unroll 4
  for (int w = 0; w < 64; ++w) {
    float4 qv = *(const float4*)&Qt[w][ty * 4];
    float4 mv = *(const float4*)&SM[w][tx * 4];
    float4 kv = *(const float4*)&Kt[w][tx * 4];
    const float* q_ = (const float*)&qv;
    const float* m_ = (const float*)&mv;
    const float* k_ = (const float*)&kv;
    #pragma unroll
    for (int i = 0; i < 4; ++i) {
      float qq = q_[i];
      #pragma unroll
      for (int j = 0; j < 4; ++j) {
        o[i][j]  = fmaf(qq, m_[j], o[i][j]);
        sc[i][j] = fmaf(qq, k_[j], sc[i][j]);
      }
    }
  }
  __syncthreads();

  #pragma unroll
  for (int i = 0; i < 4; ++i) {
    const int lt = ty * 4 + i;
    #pragma unroll
    for (int j = 0; j < 4; ++j) {
      const int ls = tx * 4 + j;
      SM[ls][lt] = (ls <= lt) ? sc[i][j] : 0.f;
    }
  }
  __syncthreads();

  #pragma unroll 4
  for (int s = 0; s < 64; ++s) {
    float4 sv = *(const float4*)&SM[s][ty * 4];
    float4 vv = *(const float4*)&Vs[s][tx * 4];
    const float* s_ = (const float*)&sv;
    const float* v_ = (const float*)&vv;
    #pragma unroll
    for (int i = 0; i < 4; ++i)
      #pragma unroll
      for (int j = 0; j < 4; ++j)
        o[i][j] = fmaf(s_[i], v_[j], o[i][j]);
  }

  const float sch = SCALE[h];
  #pragma unroll
  for (int i = 0; i < 4; ++i) {
    const int t = t0 + ty * 4 + i;
    const float fac = sch / sqrtf((float)(t + 1));
    *(float4*)&ATT[((size_t)(b * Tt + t)) * Dd + h * 64 + tx * 4] =
        make_float4(o[i][0] * fac, o[i][1] * fac, o[i][2] * fac, o[i][3] * fac);
  }
}

// ---------------------------------------------------------------------------
extern "C" void kernel_launch(void* const* d_in, const int* in_sizes, int n_in,
                              void* d_out, int out_size, void* d_ws, size_t ws_size,
                              hipStream_t stream) {
  const float* x   = (const float*)d_in[0];
  const float* Wqf = (const float*)d_in[1];
  const float* bqf = (const float*)d_in[2];
  const float* Wkf = (const float*)d_in[3];
  const float* bkf = (const float*)d_in[4];
  const float* Wqp = (const float*)d_in[5];
  const float* bqp = (const float*)d_in[6];
  const float* Wkp = (const float*)d_in[7];
  const float* bkp = (const float*)d_in[8];
  const float* Wv  = (const float*)d_in[9];
  const float* bv  = (const float*)d_in[10];
  const float* Wo  = (const float*)d_in[11];
  const float* bo  = (const float*)d_in[12];
  const float* scale = (const float*)d_in[13];

  const size_t NTOK = (size_t)Bb * Tt * Dd;  // 4,194,304
  float* qn   = (float*)d_ws;
  float* kn   = qn + NTOK;
  float* vbuf = kn + NTOK;
  float* G    = vbuf + NTOK;
  float* att  = qn;   // ALIAS (safe: see header comment)

  // merged q+k projection: grid.y = h | (which<<4)
  proj_wave2_kernel<<<dim3(Tt / 128, Hh * 2, Bb), 256, 0, stream>>>(
      x, Wqf, bqf, Wqp, bqp, Wkf, bkf, Wkp, bkp, qn, kn);

  dim3 gg((Bb * Tt) / 128, Dd / 128);  // (32, 8)
  gemm_kernel<<<gg, 256, 0, stream>>>(x, Wv, bv, vbuf);

  chunk_kv_kernel<<<dim3(NC, Hh, Bb), 256, 0, stream>>>(kn, vbuf, G);
  prefix_kernel<<<dim3(Hh, Bb), 256, 0, stream>>>(G);
  attn_chunk_kernel<<<dim3(NC, Hh, Bb), 256, 0, stream>>>(qn, kn, vbuf, G, scale, att);

  gemm_kernel<<<gg, 256, 0, stream>>>(att, Wo, bo, (float*)d_out);
}